// Round 4
// baseline (251.032 us; speedup 1.0000x reference)
//
#include <hip/hip_runtime.h>
#include <stdint.h>

// Problem constants (fixed by the reference setup):
//   logits (2,4,128,128,128) fp32, target one-hot same shape.
#define NVOX (1u << 21)            // 128^3 voxels per batch (exactly 2^21)
#define NB   2                     // batches
#define KSEL 419430u               // int(0.2 * 2^21)
#define TPB  256
#define VPB  2048                  // voxels per block  -> 8 blocks/CU (full wave cap)
#define BPB  ((int)(NVOX / VPB))   // 1024 blocks per batch
#define NBLK (NB * BPB)            // 2048 blocks
#define NCOPY 64                   // float-accumulator spreading (dice / sum_above)
#define NHC  64                    // histogram copies: 16 contending blocks per address
#define NBIN 4096                  // 12-bit radix buckets at both levels
#define L1SH 19                    // level-1 bucket = bits[30:19] (CE >= 0 so bit31=0)

__device__ __forceinline__ float wred64(float v) {
#pragma unroll
  for (int o = 32; o > 0; o >>= 1) v += __shfl_down(v, o, 64);
  return v;
}

// Pass 1: compute CE per voxel (store to ws), dice partial sums, and the
// level-1 radix histogram (bits[30:19]) into 64 spread copies.
__global__ __launch_bounds__(TPB, 8) void k1_ce_dice_hist(
    const float* __restrict__ logits, const float* __restrict__ target,
    float* __restrict__ ce, uint32_t* __restrict__ hist1,
    float* __restrict__ dice_acc /* [NCOPY][NB][12]: sp[4], num[4], cnt[4] */)
{
  __shared__ uint32_t sh[NBIN];
  const int tid = threadIdx.x;
  for (int i = tid; i < NBIN; i += TPB) sh[i] = 0;
  __syncthreads();

  const int blk = blockIdx.x;
  const int b = blk / BPB;
  const size_t v0 = (size_t)(blk % BPB) * VPB;
  const float* lg = logits + (size_t)b * 4 * NVOX + v0;
  const float* tg = target + (size_t)b * 4 * NVOX + v0;
  float* ceb = ce + ((size_t)b << 21) + v0;

  float sp[4] = {0.f,0.f,0.f,0.f}, nm[4] = {0.f,0.f,0.f,0.f}, ct[4] = {0.f,0.f,0.f,0.f};

#pragma unroll 2
  for (int i = tid * 4; i < VPB; i += TPB * 4) {
    float4 L[4], T[4];
#pragma unroll
    for (int c = 0; c < 4; ++c) {
      L[c] = *(const float4*)(lg + (size_t)c * NVOX + i);
      T[c] = *(const float4*)(tg + (size_t)c * NVOX + i);
    }
    float4 CE;
    float* cep = (float*)&CE;
#pragma unroll
    for (int j = 0; j < 4; ++j) {
      float l[4], t[4];
#pragma unroll
      for (int c = 0; c < 4; ++c) {
        l[c] = ((const float*)&L[c])[j];
        t[c] = ((const float*)&T[c])[j];
      }
      float m = fmaxf(fmaxf(l[0], l[1]), fmaxf(l[2], l[3]));
      float e[4]; float s = 0.f;
#pragma unroll
      for (int c = 0; c < 4; ++c) { e[c] = __expf(l[c] - m); s += e[c]; }
      float inv = 1.f / s;
      float lse = __logf(s);                       // s >= 1 -> lse >= 0
      float ly = l[0]*t[0] + l[1]*t[1] + l[2]*t[2] + l[3]*t[3]; // exact: t one-hot
      float cev = (m - ly) + lse;                  // >= 0 => uint bits order-monotonic
      cep[j] = cev;
      atomicAdd(&sh[__float_as_uint(cev) >> L1SH], 1u);
#pragma unroll
      for (int c = 0; c < 4; ++c) {
        float p = e[c] * inv;
        sp[c] += p;
        nm[c] += p * t[c];
        ct[c] += t[c];
      }
    }
    *(float4*)(ceb + i) = CE;
  }

  // dice: wave-reduce then one atomic per component per wave into a spread copy
#pragma unroll
  for (int c = 0; c < 4; ++c) { sp[c] = wred64(sp[c]); nm[c] = wred64(nm[c]); ct[c] = wred64(ct[c]); }
  if ((tid & 63) == 0) {
    float* dst = dice_acc + ((size_t)(blk & (NCOPY - 1)) * NB + b) * 12;
#pragma unroll
    for (int c = 0; c < 4; ++c) {
      atomicAdd(dst + c,     sp[c]);
      atomicAdd(dst + 4 + c, nm[c]);
      atomicAdd(dst + 8 + c, ct[c]);
    }
  }
  __syncthreads();
  // Flush LDS histogram into this block's spread copy (16 contenders/address).
  uint32_t* hdst = hist1 + ((size_t)b * NHC + (size_t)(blk & (NHC - 1))) * NBIN;
  for (int i = tid; i < NBIN; i += TPB) {
    uint32_t cv = sh[i];
    if (cv) atomicAdd(&hdst[i], cv);
  }
}

// Level-2 refinement over stored CE: sum values strictly above the level-1
// tie bucket; histogram bits[18:7] within the tie bucket (spread copies).
__global__ __launch_bounds__(TPB, 8) void k_pass2(
    const float* __restrict__ ce, const uint32_t* __restrict__ b1p,
    uint32_t* __restrict__ hist2, float* __restrict__ sum_above)
{
  __shared__ uint32_t sh[NBIN];
  __shared__ float wsum[TPB / 64];
  const int tid = threadIdx.x;
  for (int i = tid; i < NBIN; i += TPB) sh[i] = 0;
  __syncthreads();

  const int blk = blockIdx.x;
  const int b = blk / BPB;
  const size_t v0 = (size_t)(blk % BPB) * VPB;
  const float* cb = ce + ((size_t)b << 21) + v0;
  const uint32_t b1 = b1p[b];
  float local = 0.f;

#pragma unroll 2
  for (int i = tid * 4; i < VPB; i += TPB * 4) {
    float4 V = *(const float4*)(cb + i);
    const float* vp = (const float*)&V;
#pragma unroll
    for (int j = 0; j < 4; ++j) {
      uint32_t bits = __float_as_uint(vp[j]);
      uint32_t t12 = bits >> L1SH;
      if (t12 > b1) local += vp[j];
      else if (t12 == b1) atomicAdd(&sh[(bits >> 7) & (NBIN - 1)], 1u);
    }
  }

  local = wred64(local);
  if ((tid & 63) == 0) wsum[tid >> 6] = local;
  __syncthreads();
  if (tid == 0) {
    float t = 0.f;
#pragma unroll
    for (int w = 0; w < TPB / 64; ++w) t += wsum[w];
    if (t != 0.f) atomicAdd(&sum_above[b * NCOPY + (blk & (NCOPY - 1))], t);
  }
  uint32_t* hdst = hist2 + ((size_t)b * NHC + (size_t)(blk & (NHC - 1))) * NBIN;
  for (int i = tid; i < NBIN; i += TPB) {
    uint32_t cv = sh[i];
    if (cv) atomicAdd(&hdst[i], cv);
  }
}

// Sum the NHC spread copies (coalesced uint4 loads), then scan from the top
// for the bucket containing the k-th largest. One block per batch.
__global__ __launch_bounds__(256) void k_scan1(
    const uint32_t* __restrict__ hist,
    uint32_t* __restrict__ out_b, uint32_t* __restrict__ out_rem)
{
  const int b = blockIdx.x;
  const int tid = threadIdx.x;
  __shared__ uint32_t hsum[NBIN];   // 16 KB
  __shared__ uint32_t chunk[256];
  const uint32_t* hb = hist + (size_t)b * NHC * NBIN;
  uint4 acc[4] = {{0,0,0,0},{0,0,0,0},{0,0,0,0},{0,0,0,0}};
  for (int copy = 0; copy < NHC; ++copy) {
    const uint4* p = (const uint4*)(hb + (size_t)copy * NBIN) + tid * 4;
#pragma unroll
    for (int q = 0; q < 4; ++q) {
      uint4 v = p[q];
      acc[q].x += v.x; acc[q].y += v.y; acc[q].z += v.z; acc[q].w += v.w;
    }
  }
  uint32_t csum = 0;
#pragma unroll
  for (int q = 0; q < 4; ++q) {
    ((uint4*)&hsum[tid * 16])[q] = acc[q];
    csum += acc[q].x + acc[q].y + acc[q].z + acc[q].w;
  }
  chunk[tid] = csum;
  __syncthreads();
  if (tid == 0) {
    uint32_t k = KSEL, cum = 0;
    int ci = 255;
    for (; ci > 0; --ci) {
      uint32_t c = chunk[ci];
      if (cum + c >= k) break;
      cum += c;
    }
    int bkt = ci * 16;
    for (int j = 15; j >= 0; --j) {
      uint32_t c = hsum[ci * 16 + j];
      if (cum + c >= k) { bkt = ci * 16 + j; break; }
      cum += c;
    }
    out_b[b] = (uint32_t)bkt;
    out_rem[b] = k - cum;   // 1 <= rem <= hsum[bkt]
  }
}

// Final: sum hist2 copies + scan per batch; reconstruct the "within L1 bucket,
// above L2 tie" sum from counts x midpoint values (top 24 bits pinned; error
// <= 64 ulp/elem); combine with sum_above, tie remainder, dice -> scalar loss.
__global__ __launch_bounds__(256) void k_final(
    const uint32_t* __restrict__ hist2, const uint32_t* __restrict__ b1p,
    const uint32_t* __restrict__ rem1, const float* __restrict__ sum_above,
    const float* __restrict__ dice_acc, float* __restrict__ out)
{
  const int tid = threadIdx.x;
  __shared__ uint32_t hsum[NBIN];
  __shared__ uint32_t chunk[256];
  __shared__ uint32_t sbkt, srem;
  __shared__ float wpart[4];
  __shared__ float ts[NB];
  __shared__ float comp[24];

  for (int b = 0; b < NB; ++b) {
    const uint32_t* hb = hist2 + (size_t)b * NHC * NBIN;
    uint4 acc[4] = {{0,0,0,0},{0,0,0,0},{0,0,0,0},{0,0,0,0}};
    for (int copy = 0; copy < NHC; ++copy) {
      const uint4* p = (const uint4*)(hb + (size_t)copy * NBIN) + tid * 4;
#pragma unroll
      for (int q = 0; q < 4; ++q) {
        uint4 v = p[q];
        acc[q].x += v.x; acc[q].y += v.y; acc[q].z += v.z; acc[q].w += v.w;
      }
    }
    uint32_t csum = 0;
#pragma unroll
    for (int q = 0; q < 4; ++q) {
      ((uint4*)&hsum[tid * 16])[q] = acc[q];
      csum += acc[q].x + acc[q].y + acc[q].z + acc[q].w;
    }
    chunk[tid] = csum;
    __syncthreads();
    if (tid == 0) {
      uint32_t k = rem1[b], cum = 0;
      int ci = 255;
      for (; ci > 0; --ci) {
        uint32_t c = chunk[ci];
        if (cum + c >= k) break;
        cum += c;
      }
      int bkt = ci * 16;
      for (int j = 15; j >= 0; --j) {
        uint32_t c = hsum[ci * 16 + j];
        if (cum + c >= k) { bkt = ci * 16 + j; break; }
        cum += c;
      }
      sbkt = (uint32_t)bkt;
      srem = k - cum;          // 1 <= srem <= hsum[bkt]
    }
    __syncthreads();
    const uint32_t b1 = b1p[b];
    const int bkt = (int)sbkt;
    // Weighted sum of counts in L2 buckets strictly above the tie bucket.
    float w = 0.f;
#pragma unroll
    for (int j = 0; j < 16; ++j) {
      int bin = tid * 16 + j;
      if (bin > bkt) {
        uint32_t c = hsum[bin];
        if (c) {
          uint32_t bits = (b1 << L1SH) | ((uint32_t)bin << 7) | 64u;
          w += (float)c * __uint_as_float(bits);
        }
      }
    }
    w = wred64(w);
    if ((tid & 63) == 0) wpart[tid >> 6] = w;
    __syncthreads();
    if (tid == 0) {
      float sa = 0.f;
      for (int r = 0; r < NCOPY; ++r) sa += sum_above[b * NCOPY + r];
      uint32_t bits = (b1 << L1SH) | ((uint32_t)bkt << 7) | 64u;
      ts[b] = sa + wpart[0] + wpart[1] + wpart[2] + wpart[3]
              + (float)srem * __uint_as_float(bits);
    }
    __syncthreads();   // hsum/chunk reuse barrier for next batch
  }

  // dice: reduce the 64 spread copies of 24 components
  if (tid < 24) {
    float a = 0.f;
    for (int r = 0; r < NCOPY; ++r) a += dice_acc[(size_t)r * 24 + tid];
    comp[tid] = a;
  }
  __syncthreads();
  if (tid == 0) {
    float dl = 0.f;
#pragma unroll
    for (int b = 0; b < 2; ++b)
#pragma unroll
      for (int c = 1; c < 4; ++c) {
        float sp = comp[b * 12 + c];
        float nm = comp[b * 12 + 4 + c];
        float ct = comp[b * 12 + 8 + c];
        dl += 1.f - (2.f * nm) / (sp + ct + 1e-6f);
      }
    float topk = 0.5f * (ts[0] + ts[1]) / (float)KSEL;
    out[0] = topk + 0.5f * (dl / 6.f);
  }
}

extern "C" void kernel_launch(void* const* d_in, const int* in_sizes, int n_in,
                              void* d_out, int out_size, void* d_ws, size_t ws_size,
                              hipStream_t stream) {
  (void)in_sizes; (void)n_in; (void)out_size; (void)ws_size;
  const float* logits = (const float*)d_in[0];
  const float* target = (const float*)d_in[1];
  float* out = (float*)d_out;

  // Workspace layout: [ce: NB*NVOX floats][hist copies / scan / dice accums]
  char* ws = (char*)d_ws;
  float* ce = (float*)ws;
  const size_t CE_BYTES = (size_t)NB * NVOX * sizeof(float);   // 16 MiB
  uint32_t* small = (uint32_t*)(ws + CE_BYTES);
  uint32_t* hist1 = small;                                  // NB*NHC*NBIN (2 MiB)
  uint32_t* hist2 = hist1 + (size_t)NB * NHC * NBIN;        // NB*NHC*NBIN (2 MiB)
  uint32_t* b1   = hist2 + (size_t)NB * NHC * NBIN;
  uint32_t* rem1 = b1 + NB;
  float* sum_above = (float*)(rem1 + NB);                   // NB*NCOPY
  float* dice_acc  = sum_above + NB * NCOPY;                // NCOPY*NB*12
  const size_t SMALL_BYTES =
      (size_t)((char*)(dice_acc + (size_t)NCOPY * NB * 12) - (char*)small);

  // ws is re-poisoned to 0xAA before every launch: zero all accumulators.
  hipMemsetAsync(small, 0, SMALL_BYTES, stream);

  k1_ce_dice_hist<<<NBLK, TPB, 0, stream>>>(logits, target, ce, hist1, dice_acc);
  k_scan1<<<NB, 256, 0, stream>>>(hist1, b1, rem1);
  k_pass2<<<NBLK, TPB, 0, stream>>>(ce, b1, hist2, sum_above);
  k_final<<<1, 256, 0, stream>>>(hist2, b1, rem1, sum_above, dice_acc, out);
}

// Round 5
// 191.220 us; speedup vs baseline: 1.3128x; 1.3128x over previous
//
#include <hip/hip_runtime.h>
#include <stdint.h>

// Problem constants (fixed by the reference setup):
//   logits (2,4,128,128,128) fp32, target one-hot same shape.
#define NVOX (1u << 21)            // 128^3 voxels per batch (exactly 2^21)
#define NB   2                     // batches
#define KSEL 419430u               // int(0.2 * 2^21)
#define TPB  256
#define VPB  4096                  // voxels per block (R1's fastest data-pass shape)
#define BPB  ((int)(NVOX / VPB))   // 512 blocks per batch
#define NBLK (NB * BPB)            // 1024 blocks
#define NCOPY 64                   // dice accumulator spreading
#define NHC  16                    // histogram spread copies (32 contenders/address)
#define NBIN2 8192                 // 13-bit bins: exp(8) + mantissa(5)
#define SH2  18                    // bin = bits >> 18 (CE >= 0 so sign bit = 0)

__device__ __forceinline__ float wred64(float v) {
#pragma unroll
  for (int o = 32; o > 0; o >>= 1) v += __shfl_down(v, o, 64);
  return v;
}

// Single data pass: CE per voxel -> LDS {count,sum} histogram at 13-bit
// granularity; dice partial sums. No CE materialization, no second pass.
__global__ __launch_bounds__(TPB, 2) void k1_fused(
    const float* __restrict__ logits, const float* __restrict__ target,
    uint32_t* __restrict__ hcnt, float* __restrict__ hsum,
    float* __restrict__ dice_acc /* [NCOPY][NB][12]: sp[4], num[4], cnt[4] */)
{
  __shared__ uint32_t scnt[NBIN2];   // 32 KB
  __shared__ float    ssum[NBIN2];   // 32 KB  (total 64 KB -> 2 blocks/CU)
  const int tid = threadIdx.x;
  for (int i = tid; i < NBIN2; i += TPB) { scnt[i] = 0; ssum[i] = 0.f; }
  __syncthreads();

  const int blk = blockIdx.x;
  const int b = blk / BPB;
  const size_t v0 = (size_t)(blk % BPB) * VPB;
  const float* lg = logits + (size_t)b * 4 * NVOX + v0;
  const float* tg = target + (size_t)b * 4 * NVOX + v0;

  float sp[4] = {0.f,0.f,0.f,0.f}, nm[4] = {0.f,0.f,0.f,0.f}, ct[4] = {0.f,0.f,0.f,0.f};

  for (int i = tid * 4; i < VPB; i += TPB * 4) {
    float4 L[4], T[4];
#pragma unroll
    for (int c = 0; c < 4; ++c) {
      L[c] = *(const float4*)(lg + (size_t)c * NVOX + i);
      T[c] = *(const float4*)(tg + (size_t)c * NVOX + i);
    }
#pragma unroll
    for (int j = 0; j < 4; ++j) {
      float l[4], t[4];
#pragma unroll
      for (int c = 0; c < 4; ++c) {
        l[c] = ((const float*)&L[c])[j];
        t[c] = ((const float*)&T[c])[j];
      }
      float m = fmaxf(fmaxf(l[0], l[1]), fmaxf(l[2], l[3]));
      float e[4]; float s = 0.f;
#pragma unroll
      for (int c = 0; c < 4; ++c) { e[c] = __expf(l[c] - m); s += e[c]; }
      float inv = 1.f / s;
      float lse = __logf(s);                       // s >= 1 -> lse >= 0
      float ly = l[0]*t[0] + l[1]*t[1] + l[2]*t[2] + l[3]*t[3]; // exact: t one-hot
      float cev = (m - ly) + lse;                  // >= 0 (m >= ly, lse >= 0)
      uint32_t idx = __float_as_uint(cev) >> SH2;  // monotone in cev
      if (idx >= NBIN2) idx = NBIN2 - 1;           // paranoia; CE < 16 in practice
      atomicAdd(&scnt[idx], 1u);
      atomicAdd(&ssum[idx], cev);
#pragma unroll
      for (int c = 0; c < 4; ++c) {
        float p = e[c] * inv;
        sp[c] += p;
        nm[c] += p * t[c];
        ct[c] += t[c];
      }
    }
  }

  // dice: wave-reduce then one atomic per component per wave into a spread copy
#pragma unroll
  for (int c = 0; c < 4; ++c) { sp[c] = wred64(sp[c]); nm[c] = wred64(nm[c]); ct[c] = wred64(ct[c]); }
  if ((tid & 63) == 0) {
    float* dst = dice_acc + ((size_t)(blk & (NCOPY - 1)) * NB + b) * 12;
#pragma unroll
    for (int c = 0; c < 4; ++c) {
      atomicAdd(dst + c,     sp[c]);
      atomicAdd(dst + 4 + c, nm[c]);
      atomicAdd(dst + 8 + c, ct[c]);
    }
  }
  __syncthreads();
  // Flush LDS histogram into this block's spread copy (32 contenders/address).
  const size_t hoff = ((size_t)b * NHC + (size_t)(blk & (NHC - 1))) * NBIN2;
  uint32_t* cdst = hcnt + hoff;
  float*    sdst = hsum + hoff;
  for (int i = tid; i < NBIN2; i += TPB) {
    uint32_t cv = scnt[i];
    if (cv) {
      atomicAdd(&cdst[i], cv);
      atomicAdd(&sdst[i], ssum[i]);
    }
  }
}

// Parallel collapse of the NHC spread copies -> one {count,sum} per bin.
// Grid: NB * 8 blocks; block handles 1024 bins; fully coalesced.
__global__ __launch_bounds__(256) void k_reduce(
    const uint32_t* __restrict__ hcnt, const float* __restrict__ hsum,
    uint32_t* __restrict__ rcnt, float* __restrict__ rsum)
{
  const int b = blockIdx.x >> 3;
  const int seg = blockIdx.x & 7;
  const int base = seg * 1024 + threadIdx.x * 4;
  uint4 c = {0,0,0,0};
  float4 s = {0.f,0.f,0.f,0.f};
  for (int copy = 0; copy < NHC; ++copy) {
    const size_t off = ((size_t)b * NHC + copy) * NBIN2 + base;
    uint4 cv = *(const uint4*)(hcnt + off);
    float4 sv = *(const float4*)(hsum + off);
    c.x += cv.x; c.y += cv.y; c.z += cv.z; c.w += cv.w;
    s.x += sv.x; s.y += sv.y; s.z += sv.z; s.w += sv.w;
  }
  *(uint4*)(rcnt + (size_t)b * NBIN2 + base) = c;
  *(float4*)(rsum + (size_t)b * NBIN2 + base) = s;
}

// Final: per batch, top-down scan for the tie bin; topk_sum = exact sum of
// bins above + rem * (tie mean + uniform-density correction). Then dice.
__global__ __launch_bounds__(256) void k_final(
    const uint32_t* __restrict__ rcnt, const float* __restrict__ rsum,
    const float* __restrict__ dice_acc, float* __restrict__ out)
{
  __shared__ uint32_t shc[NBIN2];   // 32 KB
  __shared__ uint32_t chunk[256];
  __shared__ uint32_t sbkt, srem;
  __shared__ float wpart[4];
  __shared__ float ts[NB];
  __shared__ float comp[24];
  const int tid = threadIdx.x;

  for (int b = 0; b < NB; ++b) {
    const uint32_t* rc = rcnt + (size_t)b * NBIN2;
    const float*    rs = rsum + (size_t)b * NBIN2;
    uint32_t s = 0;
    for (int j = 0; j < 32; ++j) {
      uint32_t v = rc[tid * 32 + j];
      shc[tid * 32 + j] = v;
      s += v;
    }
    chunk[tid] = s;
    __syncthreads();
    if (tid == 0) {
      uint32_t k = KSEL, cum = 0;
      int ci = 255;
      for (; ci > 0; --ci) {
        uint32_t c = chunk[ci];
        if (cum + c >= k) break;
        cum += c;
      }
      int bkt = ci * 32;
      for (int j = 31; j >= 0; --j) {
        uint32_t c = shc[ci * 32 + j];
        if (cum + c >= k) { bkt = ci * 32 + j; break; }
        cum += c;
      }
      sbkt = (uint32_t)bkt;
      srem = k - cum;              // 1 <= srem <= shc[bkt]
    }
    __syncthreads();
    const int bkt = (int)sbkt;
    // Exact sum of all bins strictly above the tie bin.
    float w = 0.f;
    for (int j = 0; j < 32; ++j) {
      int bin = tid * 32 + j;
      if (bin > bkt) w += rs[bin];
    }
    w = wred64(w);
    if ((tid & 63) == 0) wpart[tid >> 6] = w;
    __syncthreads();
    if (tid == 0) {
      float cnt_t = (float)shc[bkt];
      float sum_t = rs[bkt];
      float lo = __uint_as_float((uint32_t)bkt << SH2);
      float hi = __uint_as_float((uint32_t)(bkt + 1) << SH2);
      float width = hi - lo;
      float avg = sum_t / cnt_t;
      float frac = (float)srem / cnt_t;
      // uniform-density model: mean of the top-rem subset of the tie bin
      float est = avg + (1.f - frac) * 0.5f * width;
      ts[b] = wpart[0] + wpart[1] + wpart[2] + wpart[3] + (float)srem * est;
    }
    __syncthreads();   // shc/chunk reuse barrier for next batch
  }

  // dice: reduce the 64 spread copies of 24 components
  if (tid < 24) {
    float a = 0.f;
    for (int r = 0; r < NCOPY; ++r) a += dice_acc[(size_t)r * 24 + tid];
    comp[tid] = a;
  }
  __syncthreads();
  if (tid == 0) {
    float dl = 0.f;
#pragma unroll
    for (int b = 0; b < 2; ++b)
#pragma unroll
      for (int c = 1; c < 4; ++c) {
        float sp = comp[b * 12 + c];
        float nm = comp[b * 12 + 4 + c];
        float ct = comp[b * 12 + 8 + c];
        dl += 1.f - (2.f * nm) / (sp + ct + 1e-6f);
      }
    float topk = 0.5f * (ts[0] + ts[1]) / (float)KSEL;
    out[0] = topk + 0.5f * (dl / 6.f);
  }
}

extern "C" void kernel_launch(void* const* d_in, const int* in_sizes, int n_in,
                              void* d_out, int out_size, void* d_ws, size_t ws_size,
                              hipStream_t stream) {
  (void)in_sizes; (void)n_in; (void)out_size; (void)ws_size;
  const float* logits = (const float*)d_in[0];
  const float* target = (const float*)d_in[1];
  float* out = (float*)d_out;

  // Workspace layout (all small; no CE buffer anymore):
  //   [hcnt 1MB][hsum 1MB][dice 6KB]  <- memset to 0
  //   [rcnt 64KB][rsum 64KB]          <- fully overwritten by k_reduce
  char* ws = (char*)d_ws;
  uint32_t* hcnt = (uint32_t*)ws;                          // NB*NHC*NBIN2
  float*    hsum = (float*)(hcnt + (size_t)NB * NHC * NBIN2);
  float*    dice_acc = hsum + (size_t)NB * NHC * NBIN2;    // NCOPY*NB*12
  uint32_t* rcnt = (uint32_t*)(dice_acc + (size_t)NCOPY * NB * 12);
  float*    rsum = (float*)(rcnt + (size_t)NB * NBIN2);
  const size_t ZERO_BYTES = (size_t)((char*)(dice_acc + (size_t)NCOPY * NB * 12) - ws);

  // ws is re-poisoned to 0xAA before every launch: zero the accumulators.
  hipMemsetAsync(hcnt, 0, ZERO_BYTES, stream);

  k1_fused<<<NBLK, TPB, 0, stream>>>(logits, target, hcnt, hsum, dice_acc);
  k_reduce<<<NB * 8, 256, 0, stream>>>(hcnt, hsum, rcnt, rsum);
  k_final<<<1, 256, 0, stream>>>(rcnt, rsum, dice_acc, out);
}

// Round 6
// 176.353 us; speedup vs baseline: 1.4235x; 1.0843x over previous
//
#include <hip/hip_runtime.h>
#include <stdint.h>

// Problem constants (fixed by the reference setup):
//   logits (2,4,128,128,128) fp32, target one-hot same shape.
#define NVOX (1u << 21)            // 128^3 voxels per batch (exactly 2^21)
#define NB   2                     // batches
#define KSEL 419430u               // int(0.2 * 2^21)
#define TPB  256
#define VPB  4096                  // voxels per block
#define BPB  ((int)(NVOX / VPB))   // 512 blocks per batch
#define NBLK (NB * BPB)            // 1024 blocks
#define NCOPY 64                   // dice accumulator spreading
#define NHC  16                    // histogram spread copies (64 contenders/address)
#define NBINS 4096                 // 12-bit bins: sign(0)+exp(8)+mantissa(4)
#define SH   19                    // bin = bits >> 19 (CE >= 0 so sign bit = 0)
#define FIXS 262144.0f             // 2^18 fixed-point scale for packed bin sums

__device__ __forceinline__ float wred64(float v) {
#pragma unroll
  for (int o = 32; o > 0; o >>= 1) v += __shfl_down(v, o, 64);
  return v;
}

// Single data pass: CE per voxel -> packed {count,sum} LDS histogram
// (one 64-bit LDS atomic per voxel); dice partial sums.
__global__ __launch_bounds__(TPB, 4) void k1_fused(
    const float* __restrict__ logits, const float* __restrict__ target,
    uint32_t* __restrict__ hcnt, float* __restrict__ hsum,
    float* __restrict__ dice_acc /* [NCOPY][NB][12]: sp[4], num[4], cnt[4] */)
{
  __shared__ unsigned long long hbin[NBINS];   // 32 KB -> 4 blocks/CU
  const int tid = threadIdx.x;
  for (int i = tid; i < NBINS; i += TPB) hbin[i] = 0ull;
  __syncthreads();

  const int blk = blockIdx.x;
  const int b = blk / BPB;
  const size_t v0 = (size_t)(blk % BPB) * VPB;
  const float* lg = logits + (size_t)b * 4 * NVOX + v0;
  const float* tg = target + (size_t)b * 4 * NVOX + v0;

  float sp[4] = {0.f,0.f,0.f,0.f}, nm[4] = {0.f,0.f,0.f,0.f}, ct[4] = {0.f,0.f,0.f,0.f};

  for (int i = tid * 4; i < VPB; i += TPB * 4) {
    float4 L[4], T[4];
#pragma unroll
    for (int c = 0; c < 4; ++c) {
      L[c] = *(const float4*)(lg + (size_t)c * NVOX + i);
      T[c] = *(const float4*)(tg + (size_t)c * NVOX + i);
    }
#pragma unroll
    for (int j = 0; j < 4; ++j) {
      float l[4], t[4];
#pragma unroll
      for (int c = 0; c < 4; ++c) {
        l[c] = ((const float*)&L[c])[j];
        t[c] = ((const float*)&T[c])[j];
      }
      float m = fmaxf(fmaxf(l[0], l[1]), fmaxf(l[2], l[3]));
      float e[4]; float s = 0.f;
#pragma unroll
      for (int c = 0; c < 4; ++c) { e[c] = __expf(l[c] - m); s += e[c]; }
      float inv = 1.f / s;
      float lse = __logf(s);                       // s >= 1 -> lse >= 0
      float ly = l[0]*t[0] + l[1]*t[1] + l[2]*t[2] + l[3]*t[3]; // exact: t one-hot
      float cev = (m - ly) + lse;                  // >= 0 (m >= ly, lse >= 0)
      uint32_t idx = __float_as_uint(cev) >> SH;   // monotone in cev; CE<16 -> <4096
      if (idx > NBINS - 1) idx = NBINS - 1;        // paranoia
      // count in bits[63:40]; sum as 2^18 fixed point in bits[39:0].
      // Per-block sum <= 16384 * 16 * 2^18 = 2^36 -> no carry into count.
      unsigned long long pk = (1ull << 40) | (unsigned long long)(cev * FIXS);
      atomicAdd(&hbin[idx], pk);
#pragma unroll
      for (int c = 0; c < 4; ++c) {
        float p = e[c] * inv;
        sp[c] += p;
        nm[c] += p * t[c];
        ct[c] += t[c];
      }
    }
  }

  // dice: wave-reduce then one atomic per component per wave into a spread copy
#pragma unroll
  for (int c = 0; c < 4; ++c) { sp[c] = wred64(sp[c]); nm[c] = wred64(nm[c]); ct[c] = wred64(ct[c]); }
  if ((tid & 63) == 0) {
    float* dst = dice_acc + ((size_t)(blk & (NCOPY - 1)) * NB + b) * 12;
#pragma unroll
    for (int c = 0; c < 4; ++c) {
      atomicAdd(dst + c,     sp[c]);
      atomicAdd(dst + 4 + c, nm[c]);
      atomicAdd(dst + 8 + c, ct[c]);
    }
  }
  __syncthreads();
  // Flush LDS histogram into this block's spread copy (64 contenders/address).
  const size_t hoff = ((size_t)b * NHC + (size_t)(blk & (NHC - 1))) * NBINS;
  uint32_t* cdst = hcnt + hoff;
  float*    sdst = hsum + hoff;
  for (int i = tid; i < NBINS; i += TPB) {
    unsigned long long v = hbin[i];
    if (v) {
      atomicAdd(&cdst[i], (uint32_t)(v >> 40));
      atomicAdd(&sdst[i], (float)(v & 0xFFFFFFFFFFull) * (1.0f / FIXS));
    }
  }
}

// Parallel collapse of the NHC spread copies -> one {count,sum} per bin.
// Grid: NB*4 blocks; each handles 1024 bins; fully coalesced uint4/float4.
__global__ __launch_bounds__(256) void k_reduce(
    const uint32_t* __restrict__ hcnt, const float* __restrict__ hsum,
    uint32_t* __restrict__ rcnt, float* __restrict__ rsum)
{
  const int b = blockIdx.x >> 2;
  const int seg = blockIdx.x & 3;
  const int base = seg * 1024 + threadIdx.x * 4;
  uint4 c = {0,0,0,0};
  float4 s = {0.f,0.f,0.f,0.f};
  for (int copy = 0; copy < NHC; ++copy) {
    const size_t off = ((size_t)b * NHC + copy) * NBINS + base;
    uint4 cv = *(const uint4*)(hcnt + off);
    float4 sv = *(const float4*)(hsum + off);
    c.x += cv.x; c.y += cv.y; c.z += cv.z; c.w += cv.w;
    s.x += sv.x; s.y += sv.y; s.z += sv.z; s.w += sv.w;
  }
  *(uint4*)(rcnt + (size_t)b * NBINS + base) = c;
  *(float4*)(rsum + (size_t)b * NBINS + base) = s;
}

// Final: per batch, top-down scan for the tie bin; topk_sum = exact sum of
// bins above + rem * (tie mean + uniform-density correction). Then dice.
__global__ __launch_bounds__(256) void k_final(
    const uint32_t* __restrict__ rcnt, const float* __restrict__ rsum,
    const float* __restrict__ dice_acc, float* __restrict__ out)
{
  __shared__ uint32_t shc[NBINS];   // 16 KB
  __shared__ uint32_t chunk[256];
  __shared__ uint32_t sbkt, srem;
  __shared__ float wpart[4];
  __shared__ float ts[NB];
  __shared__ float comp[24];
  const int tid = threadIdx.x;

  for (int b = 0; b < NB; ++b) {
    const uint32_t* rc = rcnt + (size_t)b * NBINS;
    const float*    rs = rsum + (size_t)b * NBINS;
    uint32_t s = 0;
#pragma unroll
    for (int q = 0; q < 4; ++q) {
      uint4 v = *(const uint4*)(rc + tid * 16 + q * 4);
      *(uint4*)&shc[tid * 16 + q * 4] = v;
      s += v.x + v.y + v.z + v.w;
    }
    chunk[tid] = s;
    __syncthreads();
    if (tid == 0) {
      uint32_t k = KSEL, cum = 0;
      int ci = 255;
      for (; ci > 0; --ci) {
        uint32_t c = chunk[ci];
        if (cum + c >= k) break;
        cum += c;
      }
      int bkt = ci * 16;
      for (int j = 15; j >= 0; --j) {
        uint32_t c = shc[ci * 16 + j];
        if (cum + c >= k) { bkt = ci * 16 + j; break; }
        cum += c;
      }
      sbkt = (uint32_t)bkt;
      srem = k - cum;              // 1 <= srem <= shc[bkt]
    }
    __syncthreads();
    const int bkt = (int)sbkt;
    // Exact sum of all bins strictly above the tie bin.
    float w = 0.f;
#pragma unroll
    for (int j = 0; j < 16; ++j) {
      int bin = tid * 16 + j;
      if (bin > bkt) w += rs[bin];
    }
    w = wred64(w);
    if ((tid & 63) == 0) wpart[tid >> 6] = w;
    __syncthreads();
    if (tid == 0) {
      float cnt_t = (float)shc[bkt];
      float sum_t = rs[bkt];
      float lo = __uint_as_float((uint32_t)bkt << SH);
      float hi = __uint_as_float((uint32_t)(bkt + 1) << SH);
      float width = hi - lo;
      float avg = sum_t / cnt_t;
      float frac = (float)srem / cnt_t;
      // uniform-density model: mean of the top-rem subset of the tie bin
      float est = avg + (1.f - frac) * 0.5f * width;
      ts[b] = wpart[0] + wpart[1] + wpart[2] + wpart[3] + (float)srem * est;
    }
    __syncthreads();   // shc/chunk reuse barrier for next batch
  }

  // dice: reduce the 64 spread copies of 24 components
  if (tid < 24) {
    float a = 0.f;
    for (int r = 0; r < NCOPY; ++r) a += dice_acc[(size_t)r * 24 + tid];
    comp[tid] = a;
  }
  __syncthreads();
  if (tid == 0) {
    float dl = 0.f;
#pragma unroll
    for (int b = 0; b < 2; ++b)
#pragma unroll
      for (int c = 1; c < 4; ++c) {
        float sp = comp[b * 12 + c];
        float nm = comp[b * 12 + 4 + c];
        float ct = comp[b * 12 + 8 + c];
        dl += 1.f - (2.f * nm) / (sp + ct + 1e-6f);
      }
    float topk = 0.5f * (ts[0] + ts[1]) / (float)KSEL;
    out[0] = topk + 0.5f * (dl / 6.f);
  }
}

extern "C" void kernel_launch(void* const* d_in, const int* in_sizes, int n_in,
                              void* d_out, int out_size, void* d_ws, size_t ws_size,
                              hipStream_t stream) {
  (void)in_sizes; (void)n_in; (void)out_size; (void)ws_size;
  const float* logits = (const float*)d_in[0];
  const float* target = (const float*)d_in[1];
  float* out = (float*)d_out;

  // Workspace layout:
  //   [hcnt 512KB][hsum 512KB][dice 6KB]  <- memset to 0
  //   [rcnt 32KB][rsum 32KB]              <- fully overwritten by k_reduce
  char* ws = (char*)d_ws;
  uint32_t* hcnt = (uint32_t*)ws;                          // NB*NHC*NBINS
  float*    hsum = (float*)(hcnt + (size_t)NB * NHC * NBINS);
  float*    dice_acc = hsum + (size_t)NB * NHC * NBINS;    // NCOPY*NB*12
  uint32_t* rcnt = (uint32_t*)(dice_acc + (size_t)NCOPY * NB * 12);
  float*    rsum = (float*)(rcnt + (size_t)NB * NBINS);
  const size_t ZERO_BYTES = (size_t)((char*)(dice_acc + (size_t)NCOPY * NB * 12) - ws);

  // ws is re-poisoned to 0xAA before every launch: zero the accumulators.
  hipMemsetAsync(hcnt, 0, ZERO_BYTES, stream);

  k1_fused<<<NBLK, TPB, 0, stream>>>(logits, target, hcnt, hsum, dice_acc);
  k_reduce<<<NB * 4, 256, 0, stream>>>(hcnt, hsum, rcnt, rsum);
  k_final<<<1, 256, 0, stream>>>(rcnt, rsum, dice_acc, out);
}